// Round 1
// baseline (555.521 us; speedup 1.0000x reference)
//
#include <hip/hip_runtime.h>

// ---------------------------------------------------------------------------
// EdgeUpdaterFrameDiff: x_down proj -> outer-concat edge bias -> 2-layer MLP
// with relu + residual -> out proj -> LayerNorm.  bf16 MFMA implementation.
//
// R5: R4 structure (64-row tile, 768 thr / 12 waves, phase barriers, LN all
// verbatim) + per-layer B-fragment register preload. Theory: R4 is latency-
// bound (MfmaUtil 23%, VALUBusy 24%, Occ 30%) on the per-iteration 16B
// L2 weight loads (~200-400cy exposed at 3 waves/SIMD). Preloading all 24
// B-frags per layer as one independent-load burst issued BEFORE the
// preceding barrier amortizes L2 latency to once/layer. 96 VGPR for frags
// + 32 acc stays under the 170-VGPR 3-waves/SIMD budget
// (__launch_bounds__(768,3) pins it). k_xdown re-gridded 64->512 blocks
// (was 2 waves/block on a quarter of the CUs -> latency-bound prep).
// ---------------------------------------------------------------------------

using bf16x8 = __attribute__((ext_vector_type(8))) __bf16;
using f32x16 = __attribute__((ext_vector_type(16))) float;

#define LPAD 392            // bf16 row stride for 384-wide LDS tiles (16B aligned)
#define OPAD 132            // f32 row stride for 128-wide LN staging

__device__ inline unsigned short f2bf(float f) {
    union { float f; unsigned int u; } v; v.f = f;
    unsigned int r = v.u + 0x7fffu + ((v.u >> 16) & 1u);   // RNE
    return (unsigned short)(r >> 16);
}
__device__ inline float bf2f(unsigned short h) {
    union { unsigned int u; float f; } v; v.u = ((unsigned int)h) << 16;
    return v.f;
}

// ---------------- prep: x_down = x @ Wd^T + bd  (bf16 out) -----------------
// R5: one block per output row (512 blocks x 128 thr) instead of 64 blocks:
// the old grid was 2 waves/block on 64 CUs -> pure latency. Wd (128KB) is
// L2-resident across re-reads.
__global__ void k_xdown(const float* __restrict__ x, const float* __restrict__ Wd,
                        const float* __restrict__ bd, unsigned short* __restrict__ xd) {
    __shared__ float sx[256];
    const int t = threadIdx.x;           // 0..127 -> output col n
    const int i = blockIdx.x;            // row 0..511
    if (t < 64) *(float4*)&sx[t * 4] = *(const float4*)&x[i * 256 + t * 4];
    __syncthreads();
    const float* wr = &Wd[t * 256];
    float sum = 0.f;
#pragma unroll 8
    for (int k = 0; k < 256; k += 4) {
        float4 wv = *(const float4*)&wr[k];
        float4 xv = *(const float4*)&sx[k];
        sum += wv.x * xv.x + wv.y * xv.y + wv.z * xv.z + wv.w * xv.w;
    }
    xd[i * 128 + t] = f2bf(sum + bd[t]);
}

// ------------- prep: swizzle weights into MFMA B-fragment order ------------
// [R1 verbatim]
__global__ void k_wswz(const float* __restrict__ W, unsigned short* __restrict__ dst, int total) {
    int c = blockIdx.x * 256 + threadIdx.x;
    if (c >= total) return;
    int lane = c & 63;
    int ks = (c >> 6) % 24;
    int nt = c / (24 * 64);
    int n = nt * 32 + (lane & 31);
    int k0 = ks * 16 + ((lane >> 5) << 3);
    const float* src = &W[n * 384 + k0];
    unsigned short tmp[8];
#pragma unroll
    for (int j = 0; j < 8; ++j) tmp[j] = f2bf(src[j]);
    *(uint4*)&dst[(size_t)c * 8] = *(const uint4*)tmp;
}

// ------------------------------- main kernel -------------------------------
__global__ __launch_bounds__(768, 3) void edge_main(
    const float* __restrict__ z, const unsigned short* __restrict__ xd,
    const unsigned short* __restrict__ W1s, const unsigned short* __restrict__ W2s,
    const unsigned short* __restrict__ Wos,
    const float* __restrict__ b1, const float* __restrict__ b2,
    const float* __restrict__ bo, const float* __restrict__ gamma,
    const float* __restrict__ beta, float* __restrict__ out)
{
    extern __shared__ char smem[];
    unsigned short* sA = (unsigned short*)smem;                    // z_in / residual, 64*LPAD bf16
    unsigned short* sH = (unsigned short*)(smem + 64 * LPAD * 2);  // h1
    float* sO = (float*)sH;                                        // overlaid: LN staging 64*OPAD f32

    const int tid = threadIdx.x;
    const int lane = tid & 63;
    const int w = tid >> 6;                   // wave 0..11
    const int i = blockIdx.x >> 3;            // 0..511   [R1 decode]
    const int j0 = (blockIdx.x & 7) << 6;     // 0..448

    const int arow = lane & 31;
    const int kof = (lane >> 5) << 3;   // 0 or 8
    const int half2 = (lane >> 5) << 2; // 0 or 4 (C/D row offset)

    // ---- issue layer-1 B-fragment preload: 24 independent 16B L2 loads ----
    // Issued before staging so the ~200-400cy L2 latency hides under the
    // HBM-bound z staging phase.
    bf16x8 b1f[24];
#pragma unroll
    for (int ks = 0; ks < 24; ++ks)
        b1f[ks] = *(const bf16x8*)&W1s[(size_t)((w * 24 + ks) * 64 + lane) * 8];

    // ---- stage z_in = [xd[i] | xd[j] | z[i,j,:]] as bf16 ----  [R1 body, stride 768]
    for (int c = tid; c < 64 * 16; c += 768) {
        int r = c >> 4, cc = (c & 15) << 3;
        *(uint4*)&sA[r * LPAD + cc] = *(const uint4*)&xd[i * 128 + cc];
        *(uint4*)&sA[r * LPAD + 128 + cc] = *(const uint4*)&xd[(j0 + r) * 128 + cc];
    }
    for (int c = tid; c < 64 * 32; c += 768) {
        int r = c >> 5, cc = (c & 31) << 2;
        float4 v = *(const float4*)&z[((size_t)((i << 9) + j0 + r) << 7) + cc];
        ushort4 o;
        o.x = f2bf(v.x); o.y = f2bf(v.y); o.z = f2bf(v.z); o.w = f2bf(v.w);
        *(ushort4*)&sA[r * LPAD + 256 + cc] = o;
    }
    __syncthreads();

    // ===== layer 1: h1 = relu(z_in @ W1^T + b1); wave w -> N-tile nt=w =====
    {
        f32x16 acc0 = {}, acc1 = {};
#pragma unroll
        for (int ks = 0; ks < 24; ++ks) {
            int k = ks * 16 + kof;
            bf16x8 a0 = *(const bf16x8*)&sA[arow * LPAD + k];
            bf16x8 a1 = *(const bf16x8*)&sA[(arow + 32) * LPAD + k];
            acc0 = __builtin_amdgcn_mfma_f32_32x32x16_bf16(a0, b1f[ks], acc0, 0, 0, 0);
            acc1 = __builtin_amdgcn_mfma_f32_32x32x16_bf16(a1, b1f[ks], acc1, 0, 0, 0);
        }
        int col = w * 32 + arow;
        float bias = b1[col];
#pragma unroll
        for (int rg = 0; rg < 16; ++rg) {
            int rr = half2 + (rg & 3) + ((rg >> 2) << 3);
            float v0 = acc0[rg] + bias; v0 = v0 > 0.f ? v0 : 0.f;
            float v1 = acc1[rg] + bias; v1 = v1 > 0.f ? v1 : 0.f;
            sH[rr * LPAD + col] = f2bf(v0);
            sH[(rr + 32) * LPAD + col] = f2bf(v1);
        }
    }

    // ---- issue layer-2 B preload before the barrier (drains with it) ----
    bf16x8 b2f[24];
#pragma unroll
    for (int ks = 0; ks < 24; ++ks)
        b2f[ks] = *(const bf16x8*)&W2s[(size_t)((w * 24 + ks) * 64 + lane) * 8];
    __syncthreads();

    // ===== layer 2: s = relu(h1 @ W2^T + b2) + z_in  (in place in sA) =====
    {
        f32x16 acc0 = {}, acc1 = {};
#pragma unroll
        for (int ks = 0; ks < 24; ++ks) {
            int k = ks * 16 + kof;
            bf16x8 a0 = *(const bf16x8*)&sH[arow * LPAD + k];
            bf16x8 a1 = *(const bf16x8*)&sH[(arow + 32) * LPAD + k];
            acc0 = __builtin_amdgcn_mfma_f32_32x32x16_bf16(a0, b2f[ks], acc0, 0, 0, 0);
            acc1 = __builtin_amdgcn_mfma_f32_32x32x16_bf16(a1, b2f[ks], acc1, 0, 0, 0);
        }
        int col = w * 32 + arow;
        float bias = b2[col];
#pragma unroll
        for (int rg = 0; rg < 16; ++rg) {
            int rr = half2 + (rg & 3) + ((rg >> 2) << 3);
            float v0 = acc0[rg] + bias; v0 = v0 > 0.f ? v0 : 0.f;
            float v1 = acc1[rg] + bias; v1 = v1 > 0.f ? v1 : 0.f;
            float r0 = bf2f(sA[rr * LPAD + col]);
            float r1 = bf2f(sA[(rr + 32) * LPAD + col]);
            sA[rr * LPAD + col] = f2bf(v0 + r0);
            sA[(rr + 32) * LPAD + col] = f2bf(v1 + r1);
        }
    }

    // ---- issue layer-3 B preload (waves 0..7) before the barrier ----
    bf16x8 bof[24];
    if (w < 8) {
        const int nt3 = w & 3;
#pragma unroll
        for (int ks = 0; ks < 24; ++ks)
            bof[ks] = *(const bf16x8*)&Wos[(size_t)((nt3 * 24 + ks) * 64 + lane) * 8];
    }
    __syncthreads();

    // ===== layer 3: out = s @ Wo^T + bo; waves 0..7 -> (mt,nt) units =====
    if (w < 8) {
        const int mt3 = w >> 2;           // M-tile 0/1
        f32x16 acc = {};
#pragma unroll
        for (int ks = 0; ks < 24; ++ks) {
            int k = ks * 16 + kof;
            bf16x8 a0 = *(const bf16x8*)&sA[(arow + mt3 * 32) * LPAD + k];
            acc = __builtin_amdgcn_mfma_f32_32x32x16_bf16(a0, bof[ks], acc, 0, 0, 0);
        }
        const int nt3 = w & 3;
        int col = nt3 * 32 + arow;
        float bias = bo[col];
#pragma unroll
        for (int rg = 0; rg < 16; ++rg) {
            int rr = mt3 * 32 + half2 + (rg & 3) + ((rg >> 2) << 3);
            sO[rr * OPAD + col] = acc[rg] + bias;
        }
    }
    __syncthreads();

    // ===================== LayerNorm + store  [R1 verbatim] =================
    if (tid < 256) {
        const int r = tid >> 2;       // row 0..63
        const int q = tid & 3;        // quarter
        float s = 0.f, ss = 0.f;
#pragma unroll
        for (int ii = 0; ii < 32; ++ii) {
            float v = sO[r * OPAD + q + (ii << 2)];
            s += v; ss += v * v;
        }
        s += __shfl_xor(s, 1);  ss += __shfl_xor(ss, 1);
        s += __shfl_xor(s, 2);  ss += __shfl_xor(ss, 2);
        const float mean = s * (1.f / 128.f);
        const float var = ss * (1.f / 128.f) - mean * mean;
        const float rstd = rsqrtf(var + 1e-5f);
        float* po = &out[((size_t)((i << 9) + j0 + r)) << 7];
#pragma unroll
        for (int ii = 0; ii < 8; ++ii) {
            int c0 = q * 32 + (ii << 2);
            float4 v = *(const float4*)&sO[r * OPAD + c0];
            float4 g = *(const float4*)&gamma[c0];
            float4 bb = *(const float4*)&beta[c0];
            float4 o;
            o.x = (v.x - mean) * rstd * g.x + bb.x;
            o.y = (v.y - mean) * rstd * g.y + bb.y;
            o.z = (v.z - mean) * rstd * g.z + bb.z;
            o.w = (v.w - mean) * rstd * g.w + bb.w;
            *(float4*)&po[c0] = o;
        }
    }
}

extern "C" void kernel_launch(void* const* d_in, const int* in_sizes, int n_in,
                              void* d_out, int out_size, void* d_ws, size_t ws_size,
                              hipStream_t stream) {
    const float* x     = (const float*)d_in[0];
    const float* z     = (const float*)d_in[1];
    const float* Wd    = (const float*)d_in[2];
    const float* bd    = (const float*)d_in[3];
    const float* W1    = (const float*)d_in[4];
    const float* b1    = (const float*)d_in[5];
    const float* W2    = (const float*)d_in[6];
    const float* b2    = (const float*)d_in[7];
    const float* Wo    = (const float*)d_in[8];
    const float* bo    = (const float*)d_in[9];
    const float* gamma = (const float*)d_in[10];
    const float* beta  = (const float*)d_in[11];
    float* out = (float*)d_out;

    unsigned short* xd  = (unsigned short*)d_ws;                       // 512*128*2   = 131072
    unsigned short* W1s = (unsigned short*)((char*)d_ws + 131072);     // 294912
    unsigned short* W2s = (unsigned short*)((char*)d_ws + 425984);     // 294912
    unsigned short* Wos = (unsigned short*)((char*)d_ws + 720896);     // 98304

    hipLaunchKernelGGL(k_xdown, dim3(512), dim3(128), 0, stream, x, Wd, bd, xd);
    hipLaunchKernelGGL(k_wswz, dim3(72), dim3(256), 0, stream, W1, W1s, 12 * 24 * 64);
    hipLaunchKernelGGL(k_wswz, dim3(72), dim3(256), 0, stream, W2, W2s, 12 * 24 * 64);
    hipLaunchKernelGGL(k_wswz, dim3(24), dim3(256), 0, stream, Wo, Wos, 4 * 24 * 64);

    const size_t smem = (size_t)(64 * LPAD * 2) * 2;   // sA + sH (sO overlaid) = 100352 B
    hipLaunchKernelGGL(edge_main, dim3(4096), dim3(768), smem, stream,
                       z, xd, W1s, W2s, Wos, b1, b2, bo, gamma, beta, out);
}

// Round 3
// 513.326 us; speedup vs baseline: 1.0822x; 1.0822x over previous
//
#include <hip/hip_runtime.h>

// ---------------------------------------------------------------------------
// EdgeUpdaterFrameDiff: x_down proj -> outer-concat edge bias -> 2-layer MLP
// with relu + residual -> out proj -> LayerNorm.  bf16 MFMA implementation.
//
// R7: proven R4 skeleton (64-row tile, 768 thr / 12 waves, phase barriers,
// staging / layer-3 / LN verbatim) with ONE change in the L1/L2 work split:
// wave w -> (row-half mt = w&1, N-tiles {ng, ng+6} with ng = w>>1), so one
// A-fragment ds_read feeds 2 MFMAs. Halves the dominant LDS A-read stream
// (1152 -> 576 ds_read_b128 per block in L1+L2). R6's 32-row restructure
// failed correctness twice across sessions -> abandoned; this keeps R4's
// verified tile/barrier/LN structure. R5 lesson kept: no min-waves arg in
// __launch_bounds__ (caused VGPR cap 84 -> scratch spills -> +90MB writes).
// Prep: 3x k_wswz merged into one launch (trim launch gaps).
// ---------------------------------------------------------------------------

using bf16x8 = __attribute__((ext_vector_type(8))) __bf16;
using f32x16 = __attribute__((ext_vector_type(16))) float;

#define LPAD 392            // bf16 row stride for 384-wide LDS tiles (16B aligned)
#define OPAD 132            // f32 row stride for 128-wide LN staging

__device__ inline unsigned short f2bf(float f) {
    union { float f; unsigned int u; } v; v.f = f;
    unsigned int r = v.u + 0x7fffu + ((v.u >> 16) & 1u);   // RNE
    return (unsigned short)(r >> 16);
}
__device__ inline float bf2f(unsigned short h) {
    union { unsigned int u; float f; } v; v.u = ((unsigned int)h) << 16;
    return v.f;
}

// ---------------- prep: x_down = x @ Wd^T + bd  (bf16 out) -----------------
// [R5 version: one block per output row — passed]
__global__ void k_xdown(const float* __restrict__ x, const float* __restrict__ Wd,
                        const float* __restrict__ bd, unsigned short* __restrict__ xd) {
    __shared__ float sx[256];
    const int t = threadIdx.x;           // 0..127 -> output col n
    const int i = blockIdx.x;            // row 0..511
    if (t < 64) *(float4*)&sx[t * 4] = *(const float4*)&x[i * 256 + t * 4];
    __syncthreads();
    const float* wr = &Wd[t * 256];
    float sum = 0.f;
#pragma unroll 8
    for (int k = 0; k < 256; k += 4) {
        float4 wv = *(const float4*)&wr[k];
        float4 xv = *(const float4*)&sx[k];
        sum += wv.x * xv.x + wv.y * xv.y + wv.z * xv.z + wv.w * xv.w;
    }
    xd[i * 128 + t] = f2bf(sum + bd[t]);
}

// ------------- prep: swizzle weights into MFMA B-fragment order ------------
// [R1 body; single launch covering W1 (blocks 0..71), W2 (72..143), Wo (144..167)]
__global__ void k_wswz3(const float* __restrict__ W1, const float* __restrict__ W2,
                        const float* __restrict__ Wo,
                        unsigned short* __restrict__ W1s, unsigned short* __restrict__ W2s,
                        unsigned short* __restrict__ Wos) {
    const int b = blockIdx.x;
    const float* W; unsigned short* dst; int c;
    if (b < 72)       { W = W1; dst = W1s; c = b * 256 + threadIdx.x; }
    else if (b < 144) { W = W2; dst = W2s; c = (b - 72) * 256 + threadIdx.x; }
    else              { W = Wo; dst = Wos; c = (b - 144) * 256 + threadIdx.x; }
    int lane = c & 63;
    int ks = (c >> 6) % 24;
    int nt = c / (24 * 64);
    int n = nt * 32 + (lane & 31);
    int k0 = ks * 16 + ((lane >> 5) << 3);
    const float* src = &W[n * 384 + k0];
    unsigned short tmp[8];
#pragma unroll
    for (int j = 0; j < 8; ++j) tmp[j] = f2bf(src[j]);
    *(uint4*)&dst[(size_t)c * 8] = *(const uint4*)tmp;
}

// ------------------------------- main kernel -------------------------------
__global__ __launch_bounds__(768) void edge_main(
    const float* __restrict__ z, const unsigned short* __restrict__ xd,
    const unsigned short* __restrict__ W1s, const unsigned short* __restrict__ W2s,
    const unsigned short* __restrict__ Wos,
    const float* __restrict__ b1, const float* __restrict__ b2,
    const float* __restrict__ bo, const float* __restrict__ gamma,
    const float* __restrict__ beta, float* __restrict__ out)
{
    extern __shared__ char smem[];
    unsigned short* sA = (unsigned short*)smem;                    // z_in / residual, 64*LPAD bf16
    unsigned short* sH = (unsigned short*)(smem + 64 * LPAD * 2);  // h1
    float* sO = (float*)sH;                                        // overlaid: LN staging 64*OPAD f32

    const int tid = threadIdx.x;
    const int lane = tid & 63;
    const int w = tid >> 6;                   // wave 0..11
    const int i = blockIdx.x >> 3;            // 0..511   [R1 decode]
    const int j0 = (blockIdx.x & 7) << 6;     // 0..448

    const int arow = lane & 31;
    const int kof = (lane >> 5) << 3;   // 0 or 8
    const int half2 = (lane >> 5) << 2; // 0 or 4 (C/D row offset)

    // R7 work split for L1/L2: row-half + two N-tiles per wave
    const int mt  = w & 1;              // row half 0/1 -> rows mt*32..mt*32+31
    const int ng  = w >> 1;             // 0..5 -> N-tiles ng and ng+6
    const int rbase = mt << 5;

    // ---- stage z_in = [xd[i] | xd[j] | z[i,j,:]] as bf16 ----  [R1/R4 verbatim]
    for (int c = tid; c < 64 * 16; c += 768) {
        int r = c >> 4, cc = (c & 15) << 3;
        *(uint4*)&sA[r * LPAD + cc] = *(const uint4*)&xd[i * 128 + cc];
        *(uint4*)&sA[r * LPAD + 128 + cc] = *(const uint4*)&xd[(j0 + r) * 128 + cc];
    }
    for (int c = tid; c < 64 * 32; c += 768) {
        int r = c >> 5, cc = (c & 31) << 2;
        float4 v = *(const float4*)&z[((size_t)((i << 9) + j0 + r) << 7) + cc];
        ushort4 o;
        o.x = f2bf(v.x); o.y = f2bf(v.y); o.z = f2bf(v.z); o.w = f2bf(v.w);
        *(ushort4*)&sA[r * LPAD + 256 + cc] = o;
    }
    __syncthreads();

    // ===== layer 1: h1 = relu(z_in @ W1^T + b1) =====
    // wave w -> rows rbase..rbase+31, N-tiles ng and ng+6 (A-frag shared).
    {
        f32x16 acc0 = {}, acc1 = {};
#pragma unroll 2
        for (int ks = 0; ks < 24; ++ks) {
            int k = ks * 16 + kof;
            bf16x8 a  = *(const bf16x8*)&sA[(rbase + arow) * LPAD + k];
            bf16x8 b0 = *(const bf16x8*)&W1s[(size_t)(((ng    ) * 24 + ks) * 64 + lane) * 8];
            bf16x8 bb1 = *(const bf16x8*)&W1s[(size_t)(((ng + 6) * 24 + ks) * 64 + lane) * 8];
            acc0 = __builtin_amdgcn_mfma_f32_32x32x16_bf16(a, b0, acc0, 0, 0, 0);
            acc1 = __builtin_amdgcn_mfma_f32_32x32x16_bf16(a, bb1, acc1, 0, 0, 0);
        }
        const int colA = ng * 32 + arow;
        const int colB = (ng + 6) * 32 + arow;
        const float biasA = b1[colA];
        const float biasB = b1[colB];
#pragma unroll
        for (int rg = 0; rg < 16; ++rg) {
            int rr = rbase + half2 + (rg & 3) + ((rg >> 2) << 3);
            float v0 = acc0[rg] + biasA; v0 = v0 > 0.f ? v0 : 0.f;
            float v1 = acc1[rg] + biasB; v1 = v1 > 0.f ? v1 : 0.f;
            sH[rr * LPAD + colA] = f2bf(v0);
            sH[rr * LPAD + colB] = f2bf(v1);
        }
    }
    __syncthreads();

    // ===== layer 2: s = relu(h1 @ W2^T + b2) + z_in  (in place in sA) =====
    {
        f32x16 acc0 = {}, acc1 = {};
#pragma unroll 2
        for (int ks = 0; ks < 24; ++ks) {
            int k = ks * 16 + kof;
            bf16x8 a  = *(const bf16x8*)&sH[(rbase + arow) * LPAD + k];
            bf16x8 b0 = *(const bf16x8*)&W2s[(size_t)(((ng    ) * 24 + ks) * 64 + lane) * 8];
            bf16x8 bb1 = *(const bf16x8*)&W2s[(size_t)(((ng + 6) * 24 + ks) * 64 + lane) * 8];
            acc0 = __builtin_amdgcn_mfma_f32_32x32x16_bf16(a, b0, acc0, 0, 0, 0);
            acc1 = __builtin_amdgcn_mfma_f32_32x32x16_bf16(a, bb1, acc1, 0, 0, 0);
        }
        const int colA = ng * 32 + arow;
        const int colB = (ng + 6) * 32 + arow;
        const float biasA = b2[colA];
        const float biasB = b2[colB];
#pragma unroll
        for (int rg = 0; rg < 16; ++rg) {
            int rr = rbase + half2 + (rg & 3) + ((rg >> 2) << 3);
            float v0 = acc0[rg] + biasA; v0 = v0 > 0.f ? v0 : 0.f;
            float v1 = acc1[rg] + biasB; v1 = v1 > 0.f ? v1 : 0.f;
            float r0 = bf2f(sA[rr * LPAD + colA]);
            float r1 = bf2f(sA[rr * LPAD + colB]);
            sA[rr * LPAD + colA] = f2bf(v0 + r0);
            sA[rr * LPAD + colB] = f2bf(v1 + r1);
        }
    }
    __syncthreads();

    // ===== layer 3: out = s @ Wo^T + bo; waves 0..7 -> (mt,nt) units =====
    // [R4 verbatim]
    if (w < 8) {
        const int mt3 = w >> 2;           // M-tile 0/1
        const int nt3 = w & 3;            // N-tile 0..3
        f32x16 acc = {};
#pragma unroll 2
        for (int ks = 0; ks < 24; ++ks) {
            int k = ks * 16 + kof;
            bf16x8 a0 = *(const bf16x8*)&sA[(arow + mt3 * 32) * LPAD + k];
            bf16x8 b = *(const bf16x8*)&Wos[(size_t)((nt3 * 24 + ks) * 64 + lane) * 8];
            acc = __builtin_amdgcn_mfma_f32_32x32x16_bf16(a0, b, acc, 0, 0, 0);
        }
        int col = nt3 * 32 + arow;
        float bias = bo[col];
#pragma unroll
        for (int rg = 0; rg < 16; ++rg) {
            int rr = mt3 * 32 + half2 + (rg & 3) + ((rg >> 2) << 3);
            sO[rr * OPAD + col] = acc[rg] + bias;
        }
    }
    __syncthreads();

    // ===================== LayerNorm + store  [R1/R4 verbatim] ==============
    if (tid < 256) {
        const int r = tid >> 2;       // row 0..63
        const int q = tid & 3;        // quarter
        float s = 0.f, ss = 0.f;
#pragma unroll
        for (int ii = 0; ii < 32; ++ii) {
            float v = sO[r * OPAD + q + (ii << 2)];
            s += v; ss += v * v;
        }
        s += __shfl_xor(s, 1);  ss += __shfl_xor(ss, 1);
        s += __shfl_xor(s, 2);  ss += __shfl_xor(ss, 2);
        const float mean = s * (1.f / 128.f);
        const float var = ss * (1.f / 128.f) - mean * mean;
        const float rstd = rsqrtf(var + 1e-5f);
        float* po = &out[((size_t)((i << 9) + j0 + r)) << 7];
#pragma unroll
        for (int ii = 0; ii < 8; ++ii) {
            int c0 = q * 32 + (ii << 2);
            float4 v = *(const float4*)&sO[r * OPAD + c0];
            float4 g = *(const float4*)&gamma[c0];
            float4 bb = *(const float4*)&beta[c0];
            float4 o;
            o.x = (v.x - mean) * rstd * g.x + bb.x;
            o.y = (v.y - mean) * rstd * g.y + bb.y;
            o.z = (v.z - mean) * rstd * g.z + bb.z;
            o.w = (v.w - mean) * rstd * g.w + bb.w;
            *(float4*)&po[c0] = o;
        }
    }
}

extern "C" void kernel_launch(void* const* d_in, const int* in_sizes, int n_in,
                              void* d_out, int out_size, void* d_ws, size_t ws_size,
                              hipStream_t stream) {
    const float* x     = (const float*)d_in[0];
    const float* z     = (const float*)d_in[1];
    const float* Wd    = (const float*)d_in[2];
    const float* bd    = (const float*)d_in[3];
    const float* W1    = (const float*)d_in[4];
    const float* b1    = (const float*)d_in[5];
    const float* W2    = (const float*)d_in[6];
    const float* b2    = (const float*)d_in[7];
    const float* Wo    = (const float*)d_in[8];
    const float* bo    = (const float*)d_in[9];
    const float* gamma = (const float*)d_in[10];
    const float* beta  = (const float*)d_in[11];
    float* out = (float*)d_out;

    unsigned short* xd  = (unsigned short*)d_ws;                       // 512*128*2   = 131072
    unsigned short* W1s = (unsigned short*)((char*)d_ws + 131072);     // 294912
    unsigned short* W2s = (unsigned short*)((char*)d_ws + 425984);     // 294912
    unsigned short* Wos = (unsigned short*)((char*)d_ws + 720896);     // 98304

    hipLaunchKernelGGL(k_xdown, dim3(512), dim3(128), 0, stream, x, Wd, bd, xd);
    hipLaunchKernelGGL(k_wswz3, dim3(168), dim3(256), 0, stream, W1, W2, Wo, W1s, W2s, Wos);

    const size_t smem = (size_t)(64 * LPAD * 2) * 2;   // sA + sH (sO overlaid) = 100352 B
    hipLaunchKernelGGL(edge_main, dim3(4096), dim3(768), smem, stream,
                       z, xd, W1s, W2s, Wos, b1, b2, bo, gamma, beta, out);
}